// Round 3
// baseline (44.910 us; speedup 1.0000x reference)
//
#include <hip/hip_runtime.h>

#define C_IN   256
#define C_OUT  128
#define H_DIM  270
#define W_DIM  480
#define N_PTS  512
#define K_CLS  5
#define KK     2304               // C_IN * 9 total K-terms, T = k*256 + ci

#define PB     16                 // points per conv block
#define CC     16                 // K-chunks
#define TERMS  (KK / CC)          // 144 K-terms per chunk

#define GATHER_BLKS (N_PTS * 3)          // (pt, dy) x 256 ci threads = 1536
#define TRANS_ELEMS (KK * C_OUT)         // 294912
#define TRANS_BLKS  ((TRANS_ELEMS + 255) / 256)  // 1152

// ---------------------------------------------------------------------------
// Kernel 1: fused prologue.
//  blocks [0, 1536): patch gather -> patch_g[n][k*256+ci]  (compact, coalesced
//     writes; scattered non-temporal backbone reads with lane-uniform masks)
//  blocks [1536, ...): weight transpose -> w_t[(k*256+ci)][co] (coalesced writes)
// Both are independent; gather (the long pole) is dispatched first, transpose
// fills in behind it on the same launch -> transpose cost fully hidden.
// ---------------------------------------------------------------------------
__global__ __launch_bounds__(256) void fused_pre(
        const float* __restrict__ bb,       // [C_IN][H][W]
        const int*   __restrict__ centers,  // [N][2] (x, y)
        const float* __restrict__ conv_w,   // [co][ci][3][3]
        float*       __restrict__ patch_g,  // [N][KK]
        float*       __restrict__ w_t)      // [KK][C_OUT]
{
    const int b = blockIdx.x;
    const int t = threadIdx.x;

    if (b < GATHER_BLKS) {
        const int pt = b / 3;
        const int dy = b - pt * 3;
        const int ci = t;
        const int cx = centers[2 * pt];      // indexes W
        const int cy = centers[2 * pt + 1];  // indexes H
        const int y  = cy + dy - 1;
        float* dst = patch_g + (size_t)pt * KK + dy * 3 * C_IN + ci;
        if (y < 0 || y >= H_DIM) {
            dst[0 * C_IN] = 0.f;
            dst[1 * C_IN] = 0.f;
            dst[2 * C_IN] = 0.f;
        } else {
            const float* row = bb + (size_t)ci * (H_DIM * W_DIM) + y * W_DIM;
            #pragma unroll
            for (int dx = 0; dx < 3; ++dx) {
                int x = cx + dx - 1;
                float v = 0.f;
                if (x >= 0 && x < W_DIM)
                    v = __builtin_nontemporal_load(row + x);
                dst[dx * C_IN] = v;
            }
        }
    } else {
        // transpose: output-indexed, coalesced writes, L2-hot scattered reads
        const int o = (b - GATHER_BLKS) * 256 + t;
        if (o < TRANS_ELEMS) {
            const int T  = o >> 7;          // k*256 + ci
            const int co = o & 127;
            const int k  = T >> 8;
            const int ci = T & 255;
            w_t[o] = conv_w[(size_t)co * KK + ci * 9 + k];
        }
    }
}

// ---------------------------------------------------------------------------
// Kernel 2: register-tiled conv-GEMM (no scattered reads left).
// Block = (chunk, point-group): 16 points x 144 K-terms -> partials.
// 256 threads = 64 co-pairs x 4 point-quarters; thread owns 2co x 4pts = 8 acc.
// Each float2 weight load feeds 8 FMAs; each broadcast b128 patch read feeds
// 8 FMAs. Partials[chunk][pt][co] summed in the head kernel (fixed order).
// ---------------------------------------------------------------------------
__global__ __launch_bounds__(256) void gather_conv(
        const float* __restrict__ patch_g,  // [N][KK]
        const float* __restrict__ w_t,      // [KK][C_OUT]
        float*       __restrict__ part)     // [CC][N_PTS][C_OUT]
{
    __shared__ float patch[PB][TERMS];      // 16 * 144 * 4B = 9.2 KB

    const int chunk = blockIdx.x & (CC - 1);
    const int ptg   = blockIdx.x >> 4;      // 32 point groups
    const int t     = threadIdx.x;

    // --- stage chunk slice: coalesced float4 loads from compact buffer ---
    for (int i = t; i < PB * TERMS / 4; i += 256) {
        const int pt = i / (TERMS / 4);
        const int j  = i - pt * (TERMS / 4);
        const int n  = ptg * PB + pt;
        const float4 v = *(const float4*)(patch_g + (size_t)n * KK
                                          + chunk * TERMS + j * 4);
        *(float4*)&patch[pt][j * 4] = v;
    }
    __syncthreads();

    // --- compute: cp = co-pair (co = 2cp, 2cp+1), q = point quarter ---
    const int cp = t & 63;
    const int q  = t >> 6;          // wave-uniform -> patch reads broadcast

    const float* wt_base = w_t + (size_t)(chunk * TERMS) * C_OUT + 2 * cp;

    float acc[4][2] = {{0.f,0.f},{0.f,0.f},{0.f,0.f},{0.f,0.f}};

    for (int g = 0; g < TERMS; g += 4) {
        const float2 w0 = *(const float2*)(wt_base + (size_t)(g + 0) * C_OUT);
        const float2 w1 = *(const float2*)(wt_base + (size_t)(g + 1) * C_OUT);
        const float2 w2 = *(const float2*)(wt_base + (size_t)(g + 2) * C_OUT);
        const float2 w3 = *(const float2*)(wt_base + (size_t)(g + 3) * C_OUT);
        #pragma unroll
        for (int p = 0; p < 4; ++p) {
            const float4 pv = *(const float4*)&patch[q * 4 + p][g];
            acc[p][0] = fmaf(pv.x, w0.x, acc[p][0]);
            acc[p][1] = fmaf(pv.x, w0.y, acc[p][1]);
            acc[p][0] = fmaf(pv.y, w1.x, acc[p][0]);
            acc[p][1] = fmaf(pv.y, w1.y, acc[p][1]);
            acc[p][0] = fmaf(pv.z, w2.x, acc[p][0]);
            acc[p][1] = fmaf(pv.z, w2.y, acc[p][1]);
            acc[p][0] = fmaf(pv.w, w3.x, acc[p][0]);
            acc[p][1] = fmaf(pv.w, w3.y, acc[p][1]);
        }
    }

    float* pout = part + ((size_t)chunk * N_PTS + ptg * PB) * C_OUT + 2 * cp;
    #pragma unroll
    for (int p = 0; p < 4; ++p) {
        *(float2*)(pout + (size_t)(q * 4 + p) * C_OUT) =
            make_float2(acc[p][0], acc[p][1]);
    }
}

// ---------------------------------------------------------------------------
// Kernel 3: head. One wave per point. Sums the CC partials (fixed order ->
// deterministic), fuses bias+relu, then logits / softmax / P / NLL partial.
// ---------------------------------------------------------------------------
__global__ __launch_bounds__(64) void head_kernel(
        const float* __restrict__ part,   // [CC][N_PTS][C_OUT]
        const float* __restrict__ conv_b, // [C_OUT]
        const float* __restrict__ fc_w,   // [K][C_OUT]
        const float* __restrict__ fc_b,   // [K]
        const float* __restrict__ L,      // [N][K]
        float*       __restrict__ P,      // [N][K]
        float*       __restrict__ loss_part) // [N]
{
    const int n    = blockIdx.x;
    const int lane = threadIdx.x;

    const float* pc = part + (size_t)n * C_OUT;
    float v0 = 0.f, v1 = 0.f;
    #pragma unroll
    for (int c = 0; c < CC; ++c) {
        v0 += pc[(size_t)c * N_PTS * C_OUT + lane];
        v1 += pc[(size_t)c * N_PTS * C_OUT + 64 + lane];
    }
    v0 = fmaxf(v0 + conv_b[lane], 0.f);
    v1 = fmaxf(v1 + conv_b[64 + lane], 0.f);

    float logit[K_CLS];
    #pragma unroll
    for (int k = 0; k < K_CLS; ++k) {
        float p = v0 * fc_w[k * C_OUT + lane] + v1 * fc_w[k * C_OUT + 64 + lane];
        #pragma unroll
        for (int off = 32; off > 0; off >>= 1)
            p += __shfl_xor(p, off, 64);
        logit[k] = p + fc_b[k];
    }

    if (lane == 0) {
        float m = logit[0];
        #pragma unroll
        for (int k = 1; k < K_CLS; ++k) m = fmaxf(m, logit[k]);
        float e[K_CLS];
        float s = 0.f;
        #pragma unroll
        for (int k = 0; k < K_CLS; ++k) { e[k] = expf(logit[k] - m); s += e[k]; }
        const float inv  = 1.f / s;
        const float logs = logf(s);
        float lp = 0.f;
        #pragma unroll
        for (int k = 0; k < K_CLS; ++k) {
            P[n * K_CLS + k] = e[k] * inv;
            lp -= L[n * K_CLS + k] * ((logit[k] - m) - logs);
        }
        loss_part[n] = lp;
    }
}

// ---------------------------------------------------------------------------
// Kernel 4: deterministic loss reduction (one block, no atomics).
// ---------------------------------------------------------------------------
__global__ __launch_bounds__(512) void reduce_loss(
        const float* __restrict__ loss_part, float* __restrict__ out) {
    __shared__ float sh[N_PTS];
    const int t = threadIdx.x;
    sh[t] = loss_part[t];
    __syncthreads();
    for (int s = N_PTS / 2; s > 0; s >>= 1) {
        if (t < s) sh[t] += sh[t + s];
        __syncthreads();
    }
    if (t == 0) out[0] = sh[0];
}

// ---------------------------------------------------------------------------
extern "C" void kernel_launch(void* const* d_in, const int* in_sizes, int n_in,
                              void* d_out, int out_size, void* d_ws, size_t ws_size,
                              hipStream_t stream) {
    const float* bb      = (const float*)d_in[0];   // backbone_map
    const int*   centers = (const int*)  d_in[1];
    const float* L       = (const float*)d_in[2];
    const float* conv_w  = (const float*)d_in[3];
    const float* conv_b  = (const float*)d_in[4];
    const float* fc_w    = (const float*)d_in[5];
    const float* fc_b    = (const float*)d_in[6];

    float* out = (float*)d_out;            // P: [0, 2560), loss: [2560]

    // workspace layout (floats)
    float* w_t       = (float*)d_ws;                        // 294912  (1.18 MB)
    float* patch_g   = w_t + TRANS_ELEMS;                   // 512*2304 (4.7 MB)
    float* part      = patch_g + (size_t)N_PTS * KK;        // 16*512*128 (4 MB)
    float* loss_part = part + (size_t)CC * N_PTS * C_OUT;   // 512

    fused_pre<<<GATHER_BLKS + TRANS_BLKS, 256, 0, stream>>>(
        bb, centers, conv_w, patch_g, w_t);
    gather_conv<<<N_PTS / PB * CC, 256, 0, stream>>>(patch_g, w_t, part);
    head_kernel<<<N_PTS, 64, 0, stream>>>(part, conv_b, fc_w, fc_b, L, out, loss_part);
    reduce_loss<<<1, N_PTS, 0, stream>>>(loss_part, out + N_PTS * K_CLS);
}

// Round 4
// 43.218 us; speedup vs baseline: 1.0392x; 1.0392x over previous
//
#include <hip/hip_runtime.h>

#define C_IN   256
#define C_OUT  128
#define H_DIM  270
#define W_DIM  480
#define N_PTS  512
#define K_CLS  5

#define PB     16                 // points per conv block
#define CC     32                 // K-chunks (ci split)
#define CI_PER (C_IN / CC)        // 8 ci per chunk
#define TERMS  (CI_PER * 9)       // 72 K-terms per chunk

// ---------------------------------------------------------------------------
// Kernel 1: transpose conv_w [co][ci][3][3] -> w_t [(ci*9+k)][co]
// (lane-coalesced weight reads for the conv kernel) + reset loss ticket.
// ---------------------------------------------------------------------------
__global__ __launch_bounds__(256) void transpose_w(
        const float* __restrict__ conv_w, float* __restrict__ w_t,
        unsigned* __restrict__ counter) {
    if (blockIdx.x == 0 && threadIdx.x == 0) counter[0] = 0u;
    int idx = blockIdx.x * blockDim.x + threadIdx.x;   // 0 .. 294911
    if (idx >= C_OUT * C_IN * 9) return;
    int co  = idx / (C_IN * 9);
    int rem = idx % (C_IN * 9);                        // ci*9 + k
    w_t[rem * C_OUT + co] = conv_w[idx];
}

// ---------------------------------------------------------------------------
// Kernel 2: register-tiled gather-conv (R2 structure, 2x K-split).
// Block = (chunk, point-group): 16 points x 72 K-terms. 1024 blocks = 4/CU
// so the scattered cold-HBM patch gather of one block overlaps the compute
// of its CU-mates. 256 threads = 64 co-pairs x 4 point-quarters; thread owns
// 2co x 4pts = 8 acc: each float2 weight load feeds 8 FMAs; each broadcast
// b128 patch read feeds 8 FMAs.
// ---------------------------------------------------------------------------
__global__ __launch_bounds__(256) void gather_conv(
        const float* __restrict__ bb,       // [C_IN][H][W]
        const int*   __restrict__ centers,  // [N][2] (x, y)
        const float* __restrict__ w_t,      // [(ci*9+k)][co]
        float*       __restrict__ part)     // [CC][N_PTS][C_OUT]
{
    __shared__ float patch[PB][TERMS];      // 16 * 72 * 4B = 4.6 KB

    const int chunk = blockIdx.x & (CC - 1);
    const int ptg   = blockIdx.x >> 5;      // 32 point groups
    const int t     = threadIdx.x;

    // --- stage: threads 0..127 handle (pt = t>>3, lci = t&7), 9 taps each ---
    if (t < PB * CI_PER) {
        const int pt  = t >> 3;
        const int lci = t & 7;
        const int ci  = chunk * CI_PER + lci;
        const int n   = ptg * PB + pt;
        const int cx  = centers[2 * n];     // indexes W  (range [0,270))
        const int cy  = centers[2 * n + 1]; // indexes H
        const float* base = bb + (size_t)ci * (H_DIM * W_DIM);
        float* dst = &patch[pt][lci * 9];
        if (cx >= 1 && cy >= 1 && cy <= H_DIM - 2) {
            // interior (98.9% of points; x+2 <= 271 < 480 always): no masks
            const float* p0 = base + (cy - 1) * W_DIM + (cx - 1);
            #pragma unroll
            for (int dy = 0; dy < 3; ++dy) {
                dst[dy * 3 + 0] = p0[dy * W_DIM + 0];
                dst[dy * 3 + 1] = p0[dy * W_DIM + 1];
                dst[dy * 3 + 2] = p0[dy * W_DIM + 2];
            }
        } else {
            #pragma unroll
            for (int dy = 0; dy < 3; ++dy) {
                int y = cy + dy - 1;
                bool yok = (y >= 0) && (y < H_DIM);
                #pragma unroll
                for (int dx = 0; dx < 3; ++dx) {
                    int x = cx + dx - 1;
                    float v = 0.f;
                    if (yok && x >= 0 && x < W_DIM) v = base[y * W_DIM + x];
                    dst[dy * 3 + dx] = v;
                }
            }
        }
    }
    __syncthreads();

    // --- compute: cp = co-pair (co = 2cp, 2cp+1), q = point quarter ---
    const int cp = t & 63;
    const int q  = t >> 6;          // wave-uniform -> patch reads broadcast

    const float* wt_base = w_t + (size_t)(chunk * TERMS) * C_OUT + 2 * cp;

    float acc[4][2] = {{0.f,0.f},{0.f,0.f},{0.f,0.f},{0.f,0.f}};

    for (int g = 0; g < TERMS; g += 4) {
        const float2 w0 = *(const float2*)(wt_base + (size_t)(g + 0) * C_OUT);
        const float2 w1 = *(const float2*)(wt_base + (size_t)(g + 1) * C_OUT);
        const float2 w2 = *(const float2*)(wt_base + (size_t)(g + 2) * C_OUT);
        const float2 w3 = *(const float2*)(wt_base + (size_t)(g + 3) * C_OUT);
        #pragma unroll
        for (int p = 0; p < 4; ++p) {
            const float4 pv = *(const float4*)&patch[q * 4 + p][g];
            acc[p][0] = fmaf(pv.x, w0.x, acc[p][0]);
            acc[p][1] = fmaf(pv.x, w0.y, acc[p][1]);
            acc[p][0] = fmaf(pv.y, w1.x, acc[p][0]);
            acc[p][1] = fmaf(pv.y, w1.y, acc[p][1]);
            acc[p][0] = fmaf(pv.z, w2.x, acc[p][0]);
            acc[p][1] = fmaf(pv.z, w2.y, acc[p][1]);
            acc[p][0] = fmaf(pv.w, w3.x, acc[p][0]);
            acc[p][1] = fmaf(pv.w, w3.y, acc[p][1]);
        }
    }

    float* pout = part + ((size_t)chunk * N_PTS + ptg * PB) * C_OUT + 2 * cp;
    #pragma unroll
    for (int p = 0; p < 4; ++p) {
        *(float2*)(pout + (size_t)(q * 4 + p) * C_OUT) =
            make_float2(acc[p][0], acc[p][1]);
    }
}

// ---------------------------------------------------------------------------
// Kernel 3: head + fused loss reduction. One wave per point: sums the CC
// partials (fixed order -> deterministic), bias+relu, logits/softmax/P/NLL.
// Last block to finish (device-scope atomic ticket) sums the 512 per-point
// losses in a fixed order -> deterministic final loss, no extra launch.
// ---------------------------------------------------------------------------
__global__ __launch_bounds__(64) void head_kernel(
        const float* __restrict__ part,   // [CC][N_PTS][C_OUT]
        const float* __restrict__ conv_b, // [C_OUT]
        const float* __restrict__ fc_w,   // [K][C_OUT]
        const float* __restrict__ fc_b,   // [K]
        const float* __restrict__ L,      // [N][K]
        float*       __restrict__ P,      // [N][K]
        float*       __restrict__ loss_part, // [N]
        unsigned*    __restrict__ counter,
        float*       __restrict__ loss_out)
{
    const int n    = blockIdx.x;
    const int lane = threadIdx.x;

    const float* pc = part + (size_t)n * C_OUT;
    float v0 = 0.f, v1 = 0.f;
    #pragma unroll
    for (int c = 0; c < CC; ++c) {
        v0 += pc[(size_t)c * N_PTS * C_OUT + lane];
        v1 += pc[(size_t)c * N_PTS * C_OUT + 64 + lane];
    }
    v0 = fmaxf(v0 + conv_b[lane], 0.f);
    v1 = fmaxf(v1 + conv_b[64 + lane], 0.f);

    float logit[K_CLS];
    #pragma unroll
    for (int k = 0; k < K_CLS; ++k) {
        float p = v0 * fc_w[k * C_OUT + lane] + v1 * fc_w[k * C_OUT + 64 + lane];
        #pragma unroll
        for (int off = 32; off > 0; off >>= 1)
            p += __shfl_xor(p, off, 64);
        logit[k] = p + fc_b[k];
    }

    unsigned ticket = 0u;
    if (lane == 0) {
        float m = logit[0];
        #pragma unroll
        for (int k = 1; k < K_CLS; ++k) m = fmaxf(m, logit[k]);
        float e[K_CLS];
        float s = 0.f;
        #pragma unroll
        for (int k = 0; k < K_CLS; ++k) { e[k] = expf(logit[k] - m); s += e[k]; }
        const float inv  = 1.f / s;
        const float logs = logf(s);
        float lp = 0.f;
        #pragma unroll
        for (int k = 0; k < K_CLS; ++k) {
            P[n * K_CLS + k] = e[k] * inv;
            lp -= L[n * K_CLS + k] * ((logit[k] - m) - logs);
        }
        loss_part[n] = lp;
        __threadfence();                    // release loss_part[n] device-wide
        ticket = atomicAdd(counter, 1u);    // device-scope by default
    }
    ticket = (unsigned)__shfl((int)ticket, 0, 64);
    if (ticket == N_PTS - 1) {
        __threadfence();                    // acquire side
        float s = 0.f;
        #pragma unroll
        for (int i = 0; i < N_PTS / 64; ++i) {
            // agent-scope atomic loads: immune to stale lines in this XCD's L2
            float v = __hip_atomic_load(&loss_part[lane * (N_PTS / 64) + i],
                                        __ATOMIC_RELAXED, __HIP_MEMORY_SCOPE_AGENT);
            s += v;                         // fixed per-lane order
        }
        #pragma unroll
        for (int off = 32; off > 0; off >>= 1)
            s += __shfl_xor(s, off, 64);    // fixed tree -> deterministic
        if (lane == 0) loss_out[0] = s;
    }
}

// ---------------------------------------------------------------------------
extern "C" void kernel_launch(void* const* d_in, const int* in_sizes, int n_in,
                              void* d_out, int out_size, void* d_ws, size_t ws_size,
                              hipStream_t stream) {
    const float* bb      = (const float*)d_in[0];   // backbone_map
    const int*   centers = (const int*)  d_in[1];
    const float* L       = (const float*)d_in[2];
    const float* conv_w  = (const float*)d_in[3];
    const float* conv_b  = (const float*)d_in[4];
    const float* fc_w    = (const float*)d_in[5];
    const float* fc_b    = (const float*)d_in[6];

    float* out = (float*)d_out;            // P: [0, 2560), loss: [2560]

    // workspace layout (floats): 294912 + 2097152 + 512 + 1 ~= 9.6 MB
    float*    w_t       = (float*)d_ws;
    float*    part      = w_t + C_OUT * C_IN * 9;
    float*    loss_part = part + (size_t)CC * N_PTS * C_OUT;
    unsigned* counter   = (unsigned*)(loss_part + N_PTS);

    transpose_w<<<(C_OUT * C_IN * 9 + 255) / 256, 256, 0, stream>>>(
        conv_w, w_t, counter);
    gather_conv<<<N_PTS / PB * CC, 256, 0, stream>>>(bb, centers, w_t, part);
    head_kernel<<<N_PTS, 64, 0, stream>>>(part, conv_b, fc_w, fc_b, L, out,
                                          loss_part, counter,
                                          out + N_PTS * K_CLS);
}

// Round 5
// 25.735 us; speedup vs baseline: 1.7451x; 1.6794x over previous
//
#include <hip/hip_runtime.h>

#define C_IN   256
#define C_OUT  128
#define H_DIM  270
#define W_DIM  480
#define N_PTS  512
#define K_CLS  5

#define PB     16                 // points per conv block
#define CC     32                 // K-chunks (ci split)
#define CI_PER (C_IN / CC)        // 8 ci per chunk
#define TERMS  (CI_PER * 9)       // 72 K-terms per chunk (contiguous in conv_w!)

// ---------------------------------------------------------------------------
// Kernel 1: gather-conv with in-block weight staging (no transpose kernel).
// Block = (chunk, point-group). Stage phase (one barrier):
//   - patch: 384 jobs (pt, lci, dy) x 3 scalar loads, plain cached (bb stays
//     L3-resident across graph replays -> NO nontemporal).
//   - weights: chunk slice is CONTIGUOUS per co: conv_w[co*2304+chunk*72 ..+72)
//     -> 9 float4 loads per thread-half, transposed into LDS w_s[T][co]
//     (bank co%32, 2 lanes/bank = free).
// Compute: 64 co-pairs x 4 point-quarters, 2co x 4pt = 8 acc/thread; weights
// from LDS (b64, 2-way = free), patch b128 wave-broadcast.
// ---------------------------------------------------------------------------
__global__ __launch_bounds__(256) void gather_conv(
        const float* __restrict__ bb,       // [C_IN][H][W]
        const int*   __restrict__ centers,  // [N][2] (x, y)
        const float* __restrict__ conv_w,   // [co][ci][3][3]
        float*       __restrict__ part)     // [CC][N_PTS][C_OUT]
{
    __shared__ float patch[PB][TERMS];      // 4.6 KB
    __shared__ float w_s[TERMS * C_OUT];    // 36.9 KB  (total 41.5 KB -> 3 blk/CU)

    const int chunk = blockIdx.x & (CC - 1);
    const int ptg   = blockIdx.x >> 5;      // 32 point groups
    const int t     = threadIdx.x;

    // --- stage patch: jobs i = (lci*3+dy)*16 + pt ---
    for (int i = t; i < PB * CI_PER * 3; i += 256) {
        const int pt  = i & 15;
        const int rem = i >> 4;             // 0..23
        const int lci = rem / 3;
        const int dy  = rem - lci * 3;
        const int n   = ptg * PB + pt;
        const int cx  = centers[2 * n];     // [0,270) ; x+1 <= 270 < 480 always
        const int cy  = centers[2 * n + 1]; // [0,270)
        const int y   = cy + dy - 1;
        float v0 = 0.f, v1 = 0.f, v2 = 0.f;
        if (y >= 0 && y < H_DIM) {
            const float* row = bb + ((size_t)(chunk * CI_PER + lci) * H_DIM + y)
                                  * W_DIM + cx;
            v1 = row[0];
            v2 = row[1];
            if (cx >= 1) v0 = row[-1];
        }
        float* dst = &patch[pt][lci * 9 + dy * 3];
        dst[0] = v0; dst[1] = v1; dst[2] = v2;
    }

    // --- stage weights: co = t>>1, half = t&1; contiguous 144B per half ---
    {
        const int co   = t >> 1;
        const int half = t & 1;
        const float* src = conv_w + (size_t)co * (C_IN * 9)
                                  + chunk * TERMS + half * (TERMS / 2);
        #pragma unroll
        for (int j = 0; j < TERMS / 8; ++j) {       // 9 float4
            const float4 w4 = *(const float4*)(src + j * 4);
            const int T = half * (TERMS / 2) + j * 4;
            w_s[(T + 0) * C_OUT + co] = w4.x;
            w_s[(T + 1) * C_OUT + co] = w4.y;
            w_s[(T + 2) * C_OUT + co] = w4.z;
            w_s[(T + 3) * C_OUT + co] = w4.w;
        }
    }
    __syncthreads();

    // --- compute: cp = co-pair (co = 2cp, 2cp+1), q = point quarter ---
    const int cp = t & 63;
    const int q  = t >> 6;          // wave-uniform -> patch reads broadcast

    float acc[4][2] = {{0.f,0.f},{0.f,0.f},{0.f,0.f},{0.f,0.f}};

    for (int g = 0; g < TERMS; g += 4) {
        const float2 w0 = *(const float2*)&w_s[(g + 0) * C_OUT + 2 * cp];
        const float2 w1 = *(const float2*)&w_s[(g + 1) * C_OUT + 2 * cp];
        const float2 w2 = *(const float2*)&w_s[(g + 2) * C_OUT + 2 * cp];
        const float2 w3 = *(const float2*)&w_s[(g + 3) * C_OUT + 2 * cp];
        #pragma unroll
        for (int p = 0; p < 4; ++p) {
            const float4 pv = *(const float4*)&patch[q * 4 + p][g];
            acc[p][0] = fmaf(pv.x, w0.x, acc[p][0]);
            acc[p][1] = fmaf(pv.x, w0.y, acc[p][1]);
            acc[p][0] = fmaf(pv.y, w1.x, acc[p][0]);
            acc[p][1] = fmaf(pv.y, w1.y, acc[p][1]);
            acc[p][0] = fmaf(pv.z, w2.x, acc[p][0]);
            acc[p][1] = fmaf(pv.z, w2.y, acc[p][1]);
            acc[p][0] = fmaf(pv.w, w3.x, acc[p][0]);
            acc[p][1] = fmaf(pv.w, w3.y, acc[p][1]);
        }
    }

    float* pout = part + ((size_t)chunk * N_PTS + ptg * PB) * C_OUT + 2 * cp;
    #pragma unroll
    for (int p = 0; p < 4; ++p) {
        *(float2*)(pout + (size_t)(q * 4 + p) * C_OUT) =
            make_float2(acc[p][0], acc[p][1]);
    }
}

// ---------------------------------------------------------------------------
// Kernel 2: head. One wave per point. Sums the CC partials (fixed order ->
// deterministic), fuses bias+relu, then logits / softmax / P / NLL partial.
// ---------------------------------------------------------------------------
__global__ __launch_bounds__(64) void head_kernel(
        const float* __restrict__ part,   // [CC][N_PTS][C_OUT]
        const float* __restrict__ conv_b, // [C_OUT]
        const float* __restrict__ fc_w,   // [K][C_OUT]
        const float* __restrict__ fc_b,   // [K]
        const float* __restrict__ L,      // [N][K]
        float*       __restrict__ P,      // [N][K]
        float*       __restrict__ loss_part) // [N]
{
    const int n    = blockIdx.x;
    const int lane = threadIdx.x;

    const float* pc = part + (size_t)n * C_OUT;
    float v0 = 0.f, v1 = 0.f;
    #pragma unroll
    for (int c = 0; c < CC; ++c) {
        v0 += pc[(size_t)c * N_PTS * C_OUT + lane];
        v1 += pc[(size_t)c * N_PTS * C_OUT + 64 + lane];
    }
    v0 = fmaxf(v0 + conv_b[lane], 0.f);
    v1 = fmaxf(v1 + conv_b[64 + lane], 0.f);

    float logit[K_CLS];
    #pragma unroll
    for (int k = 0; k < K_CLS; ++k) {
        float p = v0 * fc_w[k * C_OUT + lane] + v1 * fc_w[k * C_OUT + 64 + lane];
        #pragma unroll
        for (int off = 32; off > 0; off >>= 1)
            p += __shfl_xor(p, off, 64);
        logit[k] = p + fc_b[k];
    }

    if (lane == 0) {
        float m = logit[0];
        #pragma unroll
        for (int k = 1; k < K_CLS; ++k) m = fmaxf(m, logit[k]);
        float e[K_CLS];
        float s = 0.f;
        #pragma unroll
        for (int k = 0; k < K_CLS; ++k) { e[k] = expf(logit[k] - m); s += e[k]; }
        const float inv  = 1.f / s;
        const float logs = logf(s);
        float lp = 0.f;
        #pragma unroll
        for (int k = 0; k < K_CLS; ++k) {
            P[n * K_CLS + k] = e[k] * inv;
            lp -= L[n * K_CLS + k] * ((logit[k] - m) - logs);
        }
        loss_part[n] = lp;
    }
}

// ---------------------------------------------------------------------------
// Kernel 3: deterministic loss reduction (one block, no atomics).
// ---------------------------------------------------------------------------
__global__ __launch_bounds__(512) void reduce_loss(
        const float* __restrict__ loss_part, float* __restrict__ out) {
    __shared__ float sh[N_PTS];
    const int t = threadIdx.x;
    sh[t] = loss_part[t];
    __syncthreads();
    for (int s = N_PTS / 2; s > 0; s >>= 1) {
        if (t < s) sh[t] += sh[t + s];
        __syncthreads();
    }
    if (t == 0) out[0] = sh[0];
}

// ---------------------------------------------------------------------------
extern "C" void kernel_launch(void* const* d_in, const int* in_sizes, int n_in,
                              void* d_out, int out_size, void* d_ws, size_t ws_size,
                              hipStream_t stream) {
    const float* bb      = (const float*)d_in[0];   // backbone_map
    const int*   centers = (const int*)  d_in[1];
    const float* L       = (const float*)d_in[2];
    const float* conv_w  = (const float*)d_in[3];
    const float* conv_b  = (const float*)d_in[4];
    const float* fc_w    = (const float*)d_in[5];
    const float* fc_b    = (const float*)d_in[6];

    float* out = (float*)d_out;            // P: [0, 2560), loss: [2560]

    // workspace layout (floats): part 32*512*128 (8 MB) + loss_part
    float* part      = (float*)d_ws;
    float* loss_part = part + (size_t)CC * N_PTS * C_OUT;

    gather_conv<<<N_PTS / PB * CC, 256, 0, stream>>>(bb, centers, conv_w, part);
    head_kernel<<<N_PTS, 64, 0, stream>>>(part, conv_b, fc_w, fc_b, L, out, loss_part);
    reduce_loss<<<1, N_PTS, 0, stream>>>(loss_part, out + N_PTS * K_CLS);
}

// Round 6
// 25.322 us; speedup vs baseline: 1.7736x; 1.0163x over previous
//
#include <hip/hip_runtime.h>

#define C_IN   256
#define C_OUT  128
#define H_DIM  270
#define W_DIM  480
#define N_PTS  512
#define K_CLS  5
#define PB     16                 // points per conv block

// ---------------------------------------------------------------------------
// Kernel 1: gather-conv, templated on K-split CCT.
//   CCT=64: TERMS=36, LDS ~20.7 KB -> ~7 blocks/CU (28 waves) for latency
//   hiding of the scattered patch gather. CCT=32: R5's proven fallback.
// Stage: ALL global loads (scattered patch rows + contiguous weight runs)
// issue into registers first, then LDS writes -> the two HBM streams overlap
// inside one vmcnt window. Weights transposed into w_s[T][co] (2-way bank
// aliasing only = free). Compute: 64 co-pairs x 4 point-quarters, 8 acc/thread,
// weight float2 from LDS, patch b128 wave-broadcast.
// ---------------------------------------------------------------------------
template<int CCT>
__global__ __launch_bounds__(256) void gather_conv(
        const float* __restrict__ bb,       // [C_IN][H][W]
        const int*   __restrict__ centers,  // [N][2] (x, y)
        const float* __restrict__ conv_w,   // [co][ci][3][3]
        float*       __restrict__ part)     // [CCT][N_PTS][C_OUT]
{
    constexpr int CI_PER = C_IN / CCT;      // ci per chunk
    constexpr int TERMS  = CI_PER * 9;      // contiguous run in conv_w per co
    constexpr int JOBS   = PB * CI_PER * 3; // (pt, lci, dy) row jobs
    constexpr int NJ     = (JOBS + 255) / 256;
    constexpr int WPT    = TERMS / 2;       // weight floats per thread

    __shared__ float patch[PB][TERMS];
    __shared__ float w_s[TERMS * C_OUT];

    const int chunk = blockIdx.x % CCT;
    const int ptg   = blockIdx.x / CCT;
    const int t     = threadIdx.x;

    // --- issue scattered patch loads into registers ---
    float pv[NJ][3];
    #pragma unroll
    for (int jj = 0; jj < NJ; ++jj) {
        pv[jj][0] = pv[jj][1] = pv[jj][2] = 0.f;
        const int i = t + jj * 256;
        if (i < JOBS) {
            const int pt  = i & 15;
            const int rem = i >> 4;
            const int lci = rem / 3;
            const int dy  = rem - lci * 3;
            const int n   = ptg * PB + pt;
            const int cx  = centers[2 * n];     // [0,270); cx+1 < 480 always
            const int cy  = centers[2 * n + 1];
            const int y   = cy + dy - 1;
            if (y >= 0 && y < H_DIM) {
                const float* row = bb +
                    ((size_t)(chunk * CI_PER + lci) * H_DIM + y) * W_DIM + cx;
                pv[jj][1] = row[0];
                pv[jj][2] = row[1];
                if (cx >= 1) pv[jj][0] = row[-1];
            }
        }
    }

    // --- issue contiguous weight loads into registers (overlaps patch HBM) ---
    const int co   = t >> 1;
    const int half = t & 1;
    const float* wsrc = conv_w + (size_t)co * (C_IN * 9)
                              + chunk * TERMS + half * WPT;
    float4 wreg[WPT / 4];
    #pragma unroll
    for (int j = 0; j < WPT / 4; ++j)
        wreg[j] = *(const float4*)(wsrc + j * 4);
    float2 wtail = make_float2(0.f, 0.f);
    if constexpr ((WPT & 3) != 0)
        wtail = *(const float2*)(wsrc + (WPT / 4) * 4);

    // --- drain to LDS ---
    #pragma unroll
    for (int jj = 0; jj < NJ; ++jj) {
        const int i = t + jj * 256;
        if (i < JOBS) {
            const int pt  = i & 15;
            const int rem = i >> 4;
            const int lci = rem / 3;
            const int dy  = rem - lci * 3;
            float* dst = &patch[pt][lci * 9 + dy * 3];
            dst[0] = pv[jj][0]; dst[1] = pv[jj][1]; dst[2] = pv[jj][2];
        }
    }
    #pragma unroll
    for (int j = 0; j < WPT / 4; ++j) {
        const int T = half * WPT + j * 4;
        w_s[(T + 0) * C_OUT + co] = wreg[j].x;
        w_s[(T + 1) * C_OUT + co] = wreg[j].y;
        w_s[(T + 2) * C_OUT + co] = wreg[j].z;
        w_s[(T + 3) * C_OUT + co] = wreg[j].w;
    }
    if constexpr ((WPT & 3) != 0) {
        const int T = half * WPT + (WPT / 4) * 4;
        w_s[(T + 0) * C_OUT + co] = wtail.x;
        w_s[(T + 1) * C_OUT + co] = wtail.y;
    }
    __syncthreads();

    // --- compute: cp = co-pair (co = 2cp, 2cp+1), q = point quarter ---
    const int cp = t & 63;
    const int q  = t >> 6;          // wave-uniform -> patch reads broadcast

    float acc[4][2] = {{0.f,0.f},{0.f,0.f},{0.f,0.f},{0.f,0.f}};

    for (int g = 0; g < TERMS; g += 4) {
        const float2 w0 = *(const float2*)&w_s[(g + 0) * C_OUT + 2 * cp];
        const float2 w1 = *(const float2*)&w_s[(g + 1) * C_OUT + 2 * cp];
        const float2 w2 = *(const float2*)&w_s[(g + 2) * C_OUT + 2 * cp];
        const float2 w3 = *(const float2*)&w_s[(g + 3) * C_OUT + 2 * cp];
        #pragma unroll
        for (int p = 0; p < 4; ++p) {
            const float4 pvv = *(const float4*)&patch[q * 4 + p][g];
            acc[p][0] = fmaf(pvv.x, w0.x, acc[p][0]);
            acc[p][1] = fmaf(pvv.x, w0.y, acc[p][1]);
            acc[p][0] = fmaf(pvv.y, w1.x, acc[p][0]);
            acc[p][1] = fmaf(pvv.y, w1.y, acc[p][1]);
            acc[p][0] = fmaf(pvv.z, w2.x, acc[p][0]);
            acc[p][1] = fmaf(pvv.z, w2.y, acc[p][1]);
            acc[p][0] = fmaf(pvv.w, w3.x, acc[p][0]);
            acc[p][1] = fmaf(pvv.w, w3.y, acc[p][1]);
        }
    }

    float* pout = part + ((size_t)chunk * N_PTS + ptg * PB) * C_OUT + 2 * cp;
    #pragma unroll
    for (int p = 0; p < 4; ++p) {
        *(float2*)(pout + (size_t)(q * 4 + p) * C_OUT) =
            make_float2(acc[p][0], acc[p][1]);
    }
}

// ---------------------------------------------------------------------------
// Kernel 2: head. One wave per point. Lane owns co-pair (2l, 2l+1): float2
// chunk-sum (fixed order -> deterministic), bias+relu, logits/softmax/P/NLL.
// ---------------------------------------------------------------------------
template<int CCT>
__global__ __launch_bounds__(64) void head_kernel(
        const float* __restrict__ part,   // [CCT][N_PTS][C_OUT]
        const float* __restrict__ conv_b, // [C_OUT]
        const float* __restrict__ fc_w,   // [K][C_OUT]
        const float* __restrict__ fc_b,   // [K]
        const float* __restrict__ L,      // [N][K]
        float*       __restrict__ P,      // [N][K]
        float*       __restrict__ loss_part) // [N]
{
    const int n    = blockIdx.x;
    const int lane = threadIdx.x;

    const float* pc = part + (size_t)n * C_OUT + 2 * lane;
    float vx = 0.f, vy = 0.f;
    #pragma unroll
    for (int c = 0; c < CCT; ++c) {
        const float2 p = *(const float2*)(pc + (size_t)c * N_PTS * C_OUT);
        vx += p.x; vy += p.y;
    }
    const float2 cb = *(const float2*)&conv_b[2 * lane];
    vx = fmaxf(vx + cb.x, 0.f);
    vy = fmaxf(vy + cb.y, 0.f);

    float logit[K_CLS];
    #pragma unroll
    for (int k = 0; k < K_CLS; ++k) {
        const float2 w = *(const float2*)&fc_w[k * C_OUT + 2 * lane];
        float p = vx * w.x + vy * w.y;
        #pragma unroll
        for (int off = 32; off > 0; off >>= 1)
            p += __shfl_xor(p, off, 64);
        logit[k] = p + fc_b[k];
    }

    if (lane == 0) {
        float m = logit[0];
        #pragma unroll
        for (int k = 1; k < K_CLS; ++k) m = fmaxf(m, logit[k]);
        float e[K_CLS];
        float s = 0.f;
        #pragma unroll
        for (int k = 0; k < K_CLS; ++k) { e[k] = expf(logit[k] - m); s += e[k]; }
        const float inv  = 1.f / s;
        const float logs = logf(s);
        float lp = 0.f;
        #pragma unroll
        for (int k = 0; k < K_CLS; ++k) {
            P[n * K_CLS + k] = e[k] * inv;
            lp -= L[n * K_CLS + k] * ((logit[k] - m) - logs);
        }
        loss_part[n] = lp;
    }
}

// ---------------------------------------------------------------------------
// Kernel 3: deterministic loss reduction (one block, no atomics).
// ---------------------------------------------------------------------------
__global__ __launch_bounds__(512) void reduce_loss(
        const float* __restrict__ loss_part, float* __restrict__ out) {
    __shared__ float sh[N_PTS];
    const int t = threadIdx.x;
    sh[t] = loss_part[t];
    __syncthreads();
    for (int s = N_PTS / 2; s > 0; s >>= 1) {
        if (t < s) sh[t] += sh[t + s];
        __syncthreads();
    }
    if (t == 0) out[0] = sh[0];
}

// ---------------------------------------------------------------------------
extern "C" void kernel_launch(void* const* d_in, const int* in_sizes, int n_in,
                              void* d_out, int out_size, void* d_ws, size_t ws_size,
                              hipStream_t stream) {
    const float* bb      = (const float*)d_in[0];   // backbone_map
    const int*   centers = (const int*)  d_in[1];
    const float* L       = (const float*)d_in[2];
    const float* conv_w  = (const float*)d_in[3];
    const float* conv_b  = (const float*)d_in[4];
    const float* fc_w    = (const float*)d_in[5];
    const float* fc_b    = (const float*)d_in[6];

    float* out = (float*)d_out;            // P: [0, 2560), loss: [2560]
    float* part = (float*)d_ws;

    const size_t need64 = ((size_t)64 * N_PTS * C_OUT + N_PTS) * sizeof(float);
    if (ws_size >= need64) {
        // CC=64: 2048 conv blocks, ~7/CU; part = 16.8 MB
        float* loss_part = part + (size_t)64 * N_PTS * C_OUT;
        gather_conv<64><<<(N_PTS / PB) * 64, 256, 0, stream>>>(
            bb, centers, conv_w, part);
        head_kernel<64><<<N_PTS, 64, 0, stream>>>(
            part, conv_b, fc_w, fc_b, L, out, loss_part);
        reduce_loss<<<1, N_PTS, 0, stream>>>(loss_part, out + N_PTS * K_CLS);
    } else {
        // fallback CC=32 (R5-proven footprint: 8 MB)
        float* loss_part = part + (size_t)32 * N_PTS * C_OUT;
        gather_conv<32><<<(N_PTS / PB) * 32, 256, 0, stream>>>(
            bb, centers, conv_w, part);
        head_kernel<32><<<N_PTS, 64, 0, stream>>>(
            part, conv_b, fc_w, fc_b, L, out, loss_part);
        reduce_loss<<<1, N_PTS, 0, stream>>>(loss_part, out + N_PTS * K_CLS);
    }
}